// Round 10
// baseline (507.478 us; speedup 1.0000x reference)
//
#include <hip/hip_runtime.h>
#include <stdint.h>

// Problem constants
#define DIM    1024
#define RANK   16
#define M_TOT  8192          // 2*4096 rows of x
#define N_TOT  3072          // 3*DIM output features
#define K_TOT  1024

// GEMM tiling: block = 256x128, BK=64, 8 waves (4M x 2N), wave tile 64x64.
// Transport = round-0's reg-staged prefetch (21.8 B/cyc/CU measured on THIS
// problem -- 2.4x the best gload_lds variant, r1's 8.9). Session fill table:
// r0 reg-staged@3blk = 21.8; r1 gload@3blk = 8.9; r4-r9 gload@1blk = 7-12.
// r0's 108.8us was volume-bound (786 MB / 7.2 TB/s); this keeps its schedule
// and cuts volume to 590 MB (48 KB per block-iter, same barrier/byte density).
#define BM 256
#define BN 128
#define BK 64
#define NT (K_TOT / BK)      // 16 K-tiles, same iter count as r0

typedef __attribute__((ext_vector_type(8))) short  s8v;   // 8 x bf16 (raw bits)
typedef __attribute__((ext_vector_type(4))) float  f4v;   // MFMA acc

__device__ __forceinline__ unsigned short f2bf(float f) {
    union { float f; unsigned int u; } v; v.f = f;
    unsigned int u = v.u;
    u += 0x7FFFu + ((u >> 16) & 1u);   // round-to-nearest-even
    return (unsigned short)(u >> 16);
}

// ---------------- Kernel 1: fused prep (unchanged from round 3) ----------------
__global__ __launch_bounds__(256)
void prep(const float4* __restrict__ x, ushort4* __restrict__ xb,
          const float* __restrict__ W,
          const float* __restrict__ Aq, const float* __restrict__ Bq,
          const float* __restrict__ Ak, const float* __restrict__ Bk,
          const float* __restrict__ Av, const float* __restrict__ Bv,
          const float* __restrict__ alpha_p,
          unsigned short* __restrict__ Wb) {
    const int tid = threadIdx.x;
    if (blockIdx.x < 2048) {
        int i = blockIdx.x * 256 + tid;          // 2048*256*4 = 2097152 exact
        #pragma unroll
        for (int k = 0; k < 4; ++k) {
            float4 v = x[i];
            ushort4 o;
            o.x = f2bf(v.x); o.y = f2bf(v.y); o.z = f2bf(v.z); o.w = f2bf(v.w);
            xb[i] = o;
            i += 2048 * 256;
        }
    } else {
        const int bid2 = blockIdx.x - 2048;      // 0..191
        const int sel  = bid2 >> 6;              // 0=q 1=k 2=v
        const int rb   = bid2 & 63;              // rows rb*16..+16
        const float* Am = (sel == 0) ? Aq : (sel == 1) ? Ak : Av;  // [RANK, DIM]
        const float* Bm = (sel == 0) ? Bq : (sel == 1) ? Bk : Bv;  // [DIM, RANK]

        __shared__ float sb[16][RANK];
        {
            const int row = rb * 16 + (tid >> 4);
            sb[tid >> 4][tid & 15] = alpha_p[0] * Bm[row * RANK + (tid & 15)];
        }
        __syncthreads();

        float4 a4[RANK];                          // A column-slice, 64 VGPRs
        #pragma unroll
        for (int r = 0; r < RANK; ++r)
            a4[r] = ((const float4*)(Am + r * DIM))[tid];

        #pragma unroll
        for (int row = 0; row < 16; ++row) {
            const int o = sel * 1024 + rb * 16 + row;
            float4 w = ((const float4*)(W + (size_t)o * DIM))[tid];
            #pragma unroll
            for (int r = 0; r < RANK; ++r) {
                const float s = sb[row][r];
                w.x += s * a4[r].x; w.y += s * a4[r].y;
                w.z += s * a4[r].z; w.w += s * a4[r].w;
            }
            ushort4 ov;
            ov.x = f2bf(w.x); ov.y = f2bf(w.y); ov.z = f2bf(w.z); ov.w = f2bf(w.w);
            ((ushort4*)(Wb + (size_t)o * DIM))[tid] = ov;
        }
    }
}

// ---------------- Kernel 2: bf16 MFMA GEMM, C = Xb * Wb^T + bias ----------------
// r0's register-prefetch pipeline, re-geometried:
//   iter kk: __syncthreads();                 // all waves done reading LDS
//            ds_write 6 x b128 from regs;     // implicit vmcnt wait: prefetch
//                                             // had a FULL compute phase slack
//            __syncthreads();                 // tile published
//            issue next tile's 6 loads->regs; // decoupled issue point
//            2 ksteps x 16 MFMA from LDS
// Single 48 KB LDS buffer, 3 blocks/CU (144 KB), grid 768 = exactly 3/CU:
// zero packing waste; cross-block overlap hides each block's barrier/wait
// (r0/m97/m114 mechanism). No setprio (m190: hurts lockstep GEMM).
// LDS: 48 fragment-ordered 1 KB chunks (A 32 + B 16), chunk c: lane l owns
// halves [c*512 + l*8, +8) -- conflict-free both directions (all session).
__global__ __launch_bounds__(512, 6)
void gemm_bt(const unsigned short* __restrict__ Xb,
             const unsigned short* __restrict__ Wb,
             const float* __restrict__ bias,
             float* __restrict__ out) {
    __shared__ __align__(16) unsigned short S[48 * 512];   // 48 KB

    const int tid  = threadIdx.x;
    const int wave = tid >> 6;       // 0..7
    const int lane = tid & 63;
    const int l15  = lane & 15;
    const int lq   = lane >> 4;      // 0..3
    const int wr   = wave >> 1;      // M quadrant 0..3 (64 rows each)
    const int wc   = wave & 1;       // N half     0..1 (64 cols each)

    // XCD map (r5-proven, FETCH -> 49 MB): per XCD a 4bm x 24bn chunk,
    // bn-fastest; A-stripe (4 x 256 rows = 2 MB) L2-resident, B streams.
    // Bijective: 768 = 8 XCDs x 96.
    const int bid = blockIdx.x;
    const int xcd = bid & 7;
    const int s   = bid >> 3;        // 0..95
    const int bm  = xcd * 4 + s / 24;   // 0..31
    const int bn  = s % 24;             // 0..23

    // Staging: 48 chunks of 1 KB per K-tile (A: c 0..31, B: c 32..47).
    // A chunk c: rows (c>>1)*16 + l15 (0..255), k-cols (c&1)*32 + lq*8.
    // B chunk c-32: rows ((c-32)>>1)*16 + l15 (0..127), same k-cols.
    // Wave w owns chunks w*6 .. w*6+5 (6 loads / ds_writes per iter).
    const unsigned short* gp[6];
    unsigned short* lp[6];
    #pragma unroll
    for (int u = 0; u < 6; ++u) {
        const int c = wave * 6 + u;              // 0..47
        const int col = ((c & 1) << 5) + (lq << 3);
        if (c < 32) {
            const int row = ((c >> 1) << 4) + l15;          // 0..255
            gp[u] = Xb + (size_t)(bm * BM + row) * K_TOT + col;
        } else {
            const int row = (((c - 32) >> 1) << 4) + l15;   // 0..127
            gp[u] = Wb + (size_t)(bn * BN + row) * K_TOT + col;
        }
        lp[u] = &S[c * 512 + lane * 8];
    }

    // Prologue: prefetch tile 0 into registers.
    s8v reg[6];
    #pragma unroll
    for (int u = 0; u < 6; ++u) reg[u] = *(const s8v*)(gp[u]);

    f4v acc[4][4] = {};

    for (int kk = 0; kk < K_TOT; kk += BK) {
        __syncthreads();             // all waves done reading LDS (prev iter)
        #pragma unroll
        for (int u = 0; u < 6; ++u)
            *(s8v*)(lp[u]) = reg[u]; // implicit vmcnt wait here: near-free
        __syncthreads();             // tile published

        // Issue next tile's loads NOW; consumed only after the next barrier.
        const int kn = (kk + BK < K_TOT) ? (kk + BK) : 0;   // wrap: harmless
        #pragma unroll
        for (int u = 0; u < 6; ++u) reg[u] = *(const s8v*)(gp[u] + kn);

        const s8v* Avp = (const s8v*)S;          // A: s8v [0, 2048)
        const s8v* Bvp = (const s8v*)S + 2048;   // B: s8v [2048, 3072)
        #pragma unroll
        for (int t = 0; t < 2; ++t) {            // two k-steps of 32
            s8v af[4], bf[4];
            #pragma unroll
            for (int i = 0; i < 4; ++i) {
                af[i] = Avp[((wr * 4 + i) * 2 + t) * 64 + lane];
                bf[i] = Bvp[((wc * 4 + i) * 2 + t) * 64 + lane];
            }
            #pragma unroll
            for (int i = 0; i < 4; ++i)
                #pragma unroll
                for (int j = 0; j < 4; ++j)
                    acc[i][j] = __builtin_amdgcn_mfma_f32_16x16x32_bf16(
                        af[i], bf[j], acc[i][j], 0, 0, 0);
        }
    }

    // Epilogue: C/D layout col = lane&15, row = (lane>>4)*4 + reg  [m89]
    const int col_base = bn * BN + wc * 64;
    const int row_base = bm * BM + wr * 64 + lq * 4;
    #pragma unroll
    for (int j = 0; j < 4; ++j) {
        const int col = col_base + j * 16 + l15;
        const float bv = bias[col];
        #pragma unroll
        for (int i = 0; i < 4; ++i) {
            const int row = row_base + i * 16;
            #pragma unroll
            for (int r = 0; r < 4; ++r)
                out[(size_t)(row + r) * N_TOT + col] = acc[i][j][r] + bv;
        }
    }
}

extern "C" void kernel_launch(void* const* d_in, const int* in_sizes, int n_in,
                              void* d_out, int out_size, void* d_ws, size_t ws_size,
                              hipStream_t stream) {
    const float* x     = (const float*)d_in[0];   // [2,4096,1024]
    const float* W     = (const float*)d_in[1];   // [3072,1024]
    const float* b     = (const float*)d_in[2];   // [3072]
    const float* Aq    = (const float*)d_in[3];
    const float* Bq    = (const float*)d_in[4];
    const float* Ak    = (const float*)d_in[5];
    const float* Bk    = (const float*)d_in[6];
    const float* Av    = (const float*)d_in[7];
    const float* Bv    = (const float*)d_in[8];
    const float* alpha = (const float*)d_in[9];
    float* out = (float*)d_out;

    unsigned short* xb = (unsigned short*)d_ws;                                      // 16 MB
    unsigned short* Wb = (unsigned short*)((char*)d_ws + (size_t)M_TOT * K_TOT * 2); // +6 MB

    prep<<<2048 + 192, 256, 0, stream>>>((const float4*)x, (ushort4*)xb,
                                         W, Aq, Bq, Ak, Bk, Av, Bv, alpha, Wb);

    // 32 M-tiles x 24 N-tiles = 768 blocks = exactly 3 blocks/CU, all resident
    gemm_bt<<<(M_TOT / BM) * (N_TOT / BN), 512, 0, stream>>>(xb, Wb, b, out);
}

// Round 11
// 239.194 us; speedup vs baseline: 2.1216x; 2.1216x over previous
//
#include <hip/hip_runtime.h>
#include <stdint.h>

// Problem constants
#define DIM    1024
#define RANK   16
#define M_TOT  8192          // 2*4096 rows of x
#define N_TOT  3072          // 3*DIM output features
#define K_TOT  1024

// GEMM tiling: block = 256x256, BK=64, 8 waves (2M x 4N), wave tile 128x64.
// r6 (best, 86.5us) with HALF the sync density: ring-2 of 64 KB slots, one
// {counted vmcnt(8) + barrier} + one barrier per 64 KB staged (r6: per 32 KB).
// Register law (r7/r10 post-mortems): waves/SIMD = floor(512 / total regs);
// 256^2 tile (acc 128 + ~116 arch = 244) is hard-capped at 2 waves/SIMD =
// 1 block/CU -- volume minimization (384 MB) + sync minimization is the
// whole game at this occupancy.
#define BM 256
#define BN 256
#define BK 64
#define NT (K_TOT / BK)      // 16 K-tiles
// LDS ring: 2 slots x 64 KB (A 32 KB + B 32 KB) = 128 KB
#define SLOT_H   32768       // halves per slot
#define SLOT_V   4096        // s8v per slot
#define B_OFF_H  16384       // B region offset within slot (halves)
#define B_OFF_V  2048        // B region offset within slot (s8v)

typedef __attribute__((ext_vector_type(8))) short  s8v;   // 8 x bf16 (raw bits)
typedef __attribute__((ext_vector_type(4))) float  f4v;   // MFMA acc

__device__ __forceinline__ unsigned short f2bf(float f) {
    union { float f; unsigned int u; } v; v.f = f;
    unsigned int u = v.u;
    u += 0x7FFFu + ((u >> 16) & 1u);   // round-to-nearest-even
    return (unsigned short)(u >> 16);
}

// Async global->LDS DMA, 16 B/lane. LDS dest is wave-uniform base + lane*16;
// global src carries the fragment swizzle (m173 pattern).
__device__ __forceinline__ void gload_lds16(const unsigned short* g,
                                            unsigned short* l) {
    __builtin_amdgcn_global_load_lds(
        (const __attribute__((address_space(1))) void*)g,
        (__attribute__((address_space(3))) void*)l,
        16, 0, 0);
}

// ---------------- Kernel 1: fused prep (unchanged from round 3) ----------------
__global__ __launch_bounds__(256)
void prep(const float4* __restrict__ x, ushort4* __restrict__ xb,
          const float* __restrict__ W,
          const float* __restrict__ Aq, const float* __restrict__ Bq,
          const float* __restrict__ Ak, const float* __restrict__ Bk,
          const float* __restrict__ Av, const float* __restrict__ Bv,
          const float* __restrict__ alpha_p,
          unsigned short* __restrict__ Wb) {
    const int tid = threadIdx.x;
    if (blockIdx.x < 2048) {
        int i = blockIdx.x * 256 + tid;          // 2048*256*4 = 2097152 exact
        #pragma unroll
        for (int k = 0; k < 4; ++k) {
            float4 v = x[i];
            ushort4 o;
            o.x = f2bf(v.x); o.y = f2bf(v.y); o.z = f2bf(v.z); o.w = f2bf(v.w);
            xb[i] = o;
            i += 2048 * 256;
        }
    } else {
        const int bid2 = blockIdx.x - 2048;      // 0..191
        const int sel  = bid2 >> 6;              // 0=q 1=k 2=v
        const int rb   = bid2 & 63;              // rows rb*16..+16
        const float* Am = (sel == 0) ? Aq : (sel == 1) ? Ak : Av;  // [RANK, DIM]
        const float* Bm = (sel == 0) ? Bq : (sel == 1) ? Bk : Bv;  // [DIM, RANK]

        __shared__ float sb[16][RANK];
        {
            const int row = rb * 16 + (tid >> 4);
            sb[tid >> 4][tid & 15] = alpha_p[0] * Bm[row * RANK + (tid & 15)];
        }
        __syncthreads();

        float4 a4[RANK];                          // A column-slice, 64 VGPRs
        #pragma unroll
        for (int r = 0; r < RANK; ++r)
            a4[r] = ((const float4*)(Am + r * DIM))[tid];

        #pragma unroll
        for (int row = 0; row < 16; ++row) {
            const int o = sel * 1024 + rb * 16 + row;
            float4 w = ((const float4*)(W + (size_t)o * DIM))[tid];
            #pragma unroll
            for (int r = 0; r < RANK; ++r) {
                const float s = sb[row][r];
                w.x += s * a4[r].x; w.y += s * a4[r].y;
                w.z += s * a4[r].z; w.w += s * a4[r].w;
            }
            ushort4 ov;
            ov.x = f2bf(w.x); ov.y = f2bf(w.y); ov.z = f2bf(w.z); ov.w = f2bf(w.w);
            ((ushort4*)(Wb + (size_t)o * DIM))[tid] = ov;
        }
    }
}

// ---------------- Kernel 2: bf16 MFMA GEMM, C = Xb * Wb^T + bias ----------------
// Ring-2 / BK=64 / full-slack counted pipeline:
//   iter q: STAGE(q+1) -> slot (q+1)&1  [freed by iter q-1's ENDSYNC]
//           vmcnt(8): tile q's 8 loads landed (issued a FULL iteration ago ->
//                     near-free); q+1's 8 stay in flight (counted, never 0
//                     until the tail)
//           s_barrier: tile q published
//           COMPUTE(q): 2 ksteps x {12 ds_read_b128 + 32 MFMA (setprio)}
//           s_barrier: slot q&1 reads done (STAGE(q+2) may overwrite next iter)
// Sync density: 2 barriers + 1 wait per 64 KB staged -- half of r6, quarter
// of r9. In-flight depth 64 KB (= r6). Fence discipline = r6 (best measured).
__global__ __launch_bounds__(512, 1)
void gemm_bt(const unsigned short* __restrict__ Xb,
             const unsigned short* __restrict__ Wb,
             const float* __restrict__ bias,
             float* __restrict__ out) {
    __shared__ __align__(16) unsigned short S[2 * SLOT_H];   // 128 KB ring

    const int tid  = threadIdx.x;
    const int wave = tid >> 6;       // 0..7
    const int lane = tid & 63;
    const int l15  = lane & 15;
    const int lq   = lane >> 4;      // 0..3
    const int wr   = wave >> 2;      // M half    0..1 (128 rows)
    const int wc   = wave & 3;       // N quarter 0..3 (64 cols)

    // XCD map (r5/r6-proven, FETCH 49-60 MB): per XCD a 4bm x 12bn chunk;
    // A-stripe 2 MB L2-resident, B streams via L3. Bijective for 384 = 8x48.
    const int bid = blockIdx.x;
    const int xcd = bid & 7;
    const int s   = bid >> 3;        // 0..47
    const int bm  = xcd * 4 + s / 12;
    const int bn  = s % 12;

    // Staging: per K-tile 32 A-chunks + 32 B-chunks of 1 KB. Chunk c =
    // 16 rows x 32 k: row (c>>1)*16 + l15, k-col (c&1)*32 + lq*8 (16 B/lane).
    // Wave w owns A chunks {4w..4w+3}, B chunks {4w..4w+3} -> 8 gloads/tile.
    // LDS chunk c = wave-uniform base + lane*16B (linear DMA order; this
    // fragment-major layout: SQ_LDS_BANK_CONFLICT = 0 all session).
    const unsigned short* aptr[4];
    const unsigned short* bptr[4];
    int aoff[4], boff[4];            // chunk bases (halves) within a slot
    #pragma unroll
    for (int u = 0; u < 4; ++u) {
        const int c   = wave * 4 + u;                // 0..31
        const int row = ((c >> 1) << 4) + l15;       // 0..255
        const int col = ((c & 1) << 5) + (lq << 3);  // 0..56
        aptr[u] = Xb + (size_t)(bm * BM + row) * K_TOT + col;
        bptr[u] = Wb + (size_t)(bn * BN + row) * K_TOT + col;
        aoff[u] = c * 512;                           // A region [0, 16384)
        boff[u] = B_OFF_H + c * 512;                 // B region [16384, 32768)
    }

    #define STAGE(q)                                                         \
    {                                                                        \
        unsigned short* sl = &S[((q) & 1) * SLOT_H];                         \
        const int kk = (q) * BK;                                             \
        _Pragma("unroll")                                                    \
        for (int u = 0; u < 4; ++u) {                                        \
            gload_lds16(aptr[u] + kk, sl + aoff[u]);                         \
            gload_lds16(bptr[u] + kk, sl + boff[u]);                         \
        }                                                                    \
    }

    f4v acc[8][4] = {};

    #define COMPUTE(q)                                                       \
    {                                                                        \
        const s8v* PA = (const s8v*)S + ((q) & 1) * SLOT_V;                  \
        const s8v* PB = PA + B_OFF_V;                                        \
        _Pragma("unroll")                                                    \
        for (int t = 0; t < 2; ++t) {        /* two k-steps of 32 */         \
            s8v af[8], bf[4];                                                \
            _Pragma("unroll")                                                \
            for (int j = 0; j < 4; ++j)                                      \
                bf[j] = PB[((wc * 4 + j) * 2 + t) * 64 + lane];              \
            _Pragma("unroll")                                                \
            for (int i = 0; i < 8; ++i)                                      \
                af[i] = PA[((wr * 8 + i) * 2 + t) * 64 + lane];              \
            __builtin_amdgcn_s_setprio(1);                                   \
            _Pragma("unroll")                                                \
            for (int i = 0; i < 8; ++i)                                      \
                _Pragma("unroll")                                            \
                for (int j = 0; j < 4; ++j)                                  \
                    acc[i][j] = __builtin_amdgcn_mfma_f32_16x16x32_bf16(     \
                        af[i], bf[j], acc[i][j], 0, 0, 0);                   \
            __builtin_amdgcn_s_setprio(0);                                   \
        }                                                                    \
    }

    // Publish sync: counted vmcnt + barrier, fence-sandwiched (r6 discipline).
    #define PUBSYNC(n)                                                       \
    {                                                                        \
        __builtin_amdgcn_sched_barrier(0);                                   \
        asm volatile("s_waitcnt vmcnt(" #n ")" ::: "memory");                 \
        __builtin_amdgcn_s_barrier();                                        \
        __builtin_amdgcn_sched_barrier(0);                                   \
    }
    // Read-done sync: slot reads complete before a later STAGE overwrites it.
    #define ENDSYNC()                                                        \
    {                                                                        \
        __builtin_amdgcn_sched_barrier(0);                                   \
        __builtin_amdgcn_s_barrier();                                        \
        __builtin_amdgcn_sched_barrier(0);                                   \
    }

    // Prologue: tile 0 in flight (8 loads/wave).
    STAGE(0);

    #pragma unroll 2
    for (int q = 0; q < NT; ++q) {
        if (q + 1 < NT) {
            STAGE(q + 1);      // issue first: tile q's wait gets full-iter slack
            PUBSYNC(8);        // tile q landed; q+1's 8 stay in flight
        } else {
            PUBSYNC(0);        // last tile: drain (its loads had full slack)
        }
        COMPUTE(q);
        if (q + 1 < NT) ENDSYNC();   // slot q&1 free for STAGE(q+2)
    }
    #undef STAGE
    #undef COMPUTE
    #undef PUBSYNC
    #undef ENDSYNC

    // Epilogue: C/D layout col = lane&15, row = (lane>>4)*4 + reg  [m89]
    const int col_base = bn * BN + wc * 64;
    const int row_base = bm * BM + wr * 128 + lq * 4;
    #pragma unroll
    for (int j = 0; j < 4; ++j) {
        const int col = col_base + j * 16 + l15;
        const float bv = bias[col];
        #pragma unroll
        for (int i = 0; i < 8; ++i) {
            const int row = row_base + i * 16;
            #pragma unroll
            for (int r = 0; r < 4; ++r)
                out[(size_t)(row + r) * N_TOT + col] = acc[i][j][r] + bv;
        }
    }
}

extern "C" void kernel_launch(void* const* d_in, const int* in_sizes, int n_in,
                              void* d_out, int out_size, void* d_ws, size_t ws_size,
                              hipStream_t stream) {
    const float* x     = (const float*)d_in[0];   // [2,4096,1024]
    const float* W     = (const float*)d_in[1];   // [3072,1024]
    const float* b     = (const float*)d_in[2];   // [3072]
    const float* Aq    = (const float*)d_in[3];
    const float* Bq    = (const float*)d_in[4];
    const float* Ak    = (const float*)d_in[5];
    const float* Bk    = (const float*)d_in[6];
    const float* Av    = (const float*)d_in[7];
    const float* Bv    = (const float*)d_in[8];
    const float* alpha = (const float*)d_in[9];
    float* out = (float*)d_out;

    unsigned short* xb = (unsigned short*)d_ws;                                      // 16 MB
    unsigned short* Wb = (unsigned short*)((char*)d_ws + (size_t)M_TOT * K_TOT * 2); // +6 MB

    prep<<<2048 + 192, 256, 0, stream>>>((const float4*)x, (ushort4*)xb,
                                         W, Aq, Bq, Ak, Bk, Av, Bv, alpha, Wb);

    // 32 M-tiles x 12 N-tiles = 384 blocks
    gemm_bt<<<(M_TOT / BM) * (N_TOT / BN), 512, 0, stream>>>(xb, Wb, b, out);
}